// Round 2
// baseline (296.928 us; speedup 1.0000x reference)
//
#include <hip/hip_runtime.h>

// ChannelBlockImportanceGate: B=8, C=256, H=W=132, BLOCK=8, KEEP_RATIO=0.25
// Output = hard top-72 block mask (of 289 blocks) upsampled 8x, per (b,c) plane.
// Straight-through soft blend cancels numerically -> output is the hard mask.
//
// R1: block-ownership phase 1 (16B/lane float4 loads, all 256 lanes active,
// 1 barrier instead of 34, no s_col LDS -> no bank conflicts). fp64 scores
// keep selection exact (gaps ~1e-4 >> fp64 noise ~1e-16).

#define HH 132
#define WW 132
#define NB 17          // blocks per side (ceil(132/8) = 17)
#define TOTAL 289      // NB*NB
#define KEEP 72        // round(289*0.25)
#define NTHREADS 256
#define ROWV (WW / 4)  // 33 float4 per row

__global__ __launch_bounds__(NTHREADS)
void gate_kernel(const float* __restrict__ feats,
                 const int* __restrict__ enabled_p,
                 float* __restrict__ out) {
    const int plane = blockIdx.x;            // b*C + c, 0..2047
    const int t = threadIdx.x;
    const float* __restrict__ fp = feats + (size_t)plane * (HH * WW);
    float* __restrict__ op = out + (size_t)plane * (HH * WW);

    __shared__ double s_score[TOTAL];        // block |x| sums (fp64-exact)
    __shared__ float  s_hard[TOTAL];         // 0/1 mask per block

    // ---- Phase 1: each thread owns block(s); 8x8 patch = 16 float4 loads ----
    for (int blk = t; blk < TOTAL; blk += NTHREADS) {
        const int br = blk / NB;             // 0..16
        const int bc = blk - br * NB;        // 0..16
        const int nr = (br == NB - 1) ? 4 : 8;   // last block-row: rows 128..131
        const float4* __restrict__ p =
            (const float4*)(fp + (size_t)(br * 8) * WW) + bc * 2;
        double acc0 = 0.0, acc1 = 0.0;
        if (bc < NB - 1) {                   // full 8-wide block: 2 float4/row
            #pragma unroll
            for (int r = 0; r < 8; ++r) {
                if (r < nr) {
                    const float4 a = p[0];
                    const float4 b = p[1];
                    acc0 += (double)fabsf(a.x); acc1 += (double)fabsf(a.y);
                    acc0 += (double)fabsf(a.z); acc1 += (double)fabsf(a.w);
                    acc0 += (double)fabsf(b.x); acc1 += (double)fabsf(b.y);
                    acc0 += (double)fabsf(b.z); acc1 += (double)fabsf(b.w);
                }
                p += ROWV;
            }
        } else {                             // last block-col: cols 128..131 only
            #pragma unroll
            for (int r = 0; r < 8; ++r) {
                if (r < nr) {
                    const float4 a = p[0];
                    acc0 += (double)fabsf(a.x); acc1 += (double)fabsf(a.y);
                    acc0 += (double)fabsf(a.z); acc1 += (double)fabsf(a.w);
                }
                p += ROWV;
            }
        }
        s_score[blk] = acc0 + acc1;          // mean = /64 is monotone -> skip
    }
    __syncthreads();

    // ---- Phase 2: top-72 by stable rank (matches lax.top_k tie-break) ----
    const int en = *enabled_p;
    for (int i = t; i < TOTAL; i += NTHREADS) {
        const double si = s_score[i];
        int rank = 0;
        for (int j = 0; j < TOTAL; ++j) {    // broadcast LDS reads, conflict-free
            const double sj = s_score[j];
            rank += (int)((sj > si) || ((sj == si) && (j < i)));
        }
        s_hard[i] = (!en || rank < KEEP) ? 1.0f : 0.0f;
    }
    __syncthreads();

    // ---- Phase 3: upsample 8x, float4 stores. 4-aligned quads never cross
    // an 8-wide block boundary -> one mask value per float4. ----
    constexpr int NV = (HH * WW) / 4;        // 4356 float4s per plane
    float4* __restrict__ op4 = (float4*)op;
    for (int v = t; v < NV; v += NTHREADS) {
        const int base = v * 4;
        const int row = base / WW;           // magic-mul division
        const int col = base - row * WW;
        const float m = s_hard[(row >> 3) * NB + (col >> 3)];
        op4[v] = make_float4(m, m, m, m);
    }
}

extern "C" void kernel_launch(void* const* d_in, const int* in_sizes, int n_in,
                              void* d_out, int out_size, void* d_ws, size_t ws_size,
                              hipStream_t stream) {
    const float* feats = (const float*)d_in[0];
    const int* enabled = (const int*)d_in[1];
    float* out = (float*)d_out;
    const int planes = 8 * 256;              // B*C = 2048
    gate_kernel<<<planes, NTHREADS, 0, stream>>>(feats, enabled, out);
}